// Round 18
// baseline (359.073 us; speedup 1.0000x reference)
//
#include <hip/hip_runtime.h>

// GATConv: N=50000, NIN=128, H=4, C=16 (HC=64), E=800000 (+N self-loops,
// synthesized inside k_gat). Slot-table aggregation (no CSR). Scatter split:
// k_bin reads edges ONCE and bins by dst partition (r17 lesson: 8x edge-list
// re-read at ~600GB/s == the whole 53us); k_scatter2 consumes bins XCD-locally.
#define NN 50000
#define NIN 128
#define NH 4
#define NC 16
#define HC 64
#define NE 800000
#define NEG_SLOPE 0.2f
#define RPB 16                       // rows per block in k_xw (LDS 40KB -> 4 blk/CU)
#define NPART 8                      // dst partitions (== XCD count)
#define DPP (NN / NPART)             // 6250 dst per partition
#define GPB 1563                     // gat blocks per partition = ceil(6250/4)
#define CAP 32                       // slots per destination
#define OFCAP 1024                   // overflow list capacity
#define NGROUPS (NE / 4)             // 200000 int4 edge groups
#define BNBLK 512                    // k_bin blocks
#define BNITER ((NGROUPS + BNBLK * 256 - 1) / (BNBLK * 256))  // 2
#define BINCAP 102400                // per-partition bin capacity (mean 100k, +8sd)
#define S2CHUNK 64                   // blocks per partition in k_scatter2

__device__ __forceinline__ ushort f2bf(float v) {  // RNE f32->bf16
  unsigned u = __float_as_uint(v);
  return (ushort)((u + 0x7FFFu + ((u >> 16) & 1u)) >> 16);
}
__device__ __forceinline__ float bf2f(ushort b) {
  return __uint_as_float((unsigned)b << 16);
}
__device__ __forceinline__ float lrelu_exp(float e) {
  e = e > 0.f ? e : NEG_SLOPE * e;
  return __expf(fminf(e, 60.f));  // no max-shift needed: |e|<~12 on this data
}

// xw(bf16) = x @ W (Ws+xs in LDS, 16 rows/block, 4 rows/thread), att dots fused.
// Also zeroes cnt[]/binctr[]/ofcnt (free ride; consumers run strictly after).
__global__ __launch_bounds__(256, 4) void k_xw(
    const float* __restrict__ x, const float* __restrict__ W,
    const float* __restrict__ att_src, const float* __restrict__ att_dst,
    ushort* __restrict__ xwb, float* __restrict__ a_src, float* __restrict__ a_dst,
    int* __restrict__ cnt, int* __restrict__ binctr, int* __restrict__ ofcnt) {
  __shared__ float Ws[NIN][HC];   // 32 KB
  __shared__ float xs[RPB][NIN];  // 8 KB
  int tid = threadIdx.x;
  int gi = blockIdx.x * 256 + tid;
  if (gi < NN) cnt[gi] = 0;
  if (gi < NPART) binctr[gi] = 0;
  if (gi == NPART) *ofcnt = 0;
  int row0 = blockIdx.x * RPB;  // NN % RPB == 0
  {
    const float4* wsrc = (const float4*)W;
    float4* wdst = (float4*)&Ws[0][0];
    for (int i = tid; i < NIN * HC / 4; i += 256) wdst[i] = wsrc[i];
    const float4* xsrc = (const float4*)(x + (size_t)row0 * NIN);
    float4* xdst = (float4*)&xs[0][0];
    for (int i = tid; i < RPB * (NIN / 4); i += 256) xdst[i] = xsrc[i];
  }
  __syncthreads();
  int j = tid & 63;
  int r4 = (tid >> 6) * 4;  // this wave's 4 rows
  float acc[4] = {0.f, 0.f, 0.f, 0.f};
#pragma unroll 2
  for (int k0 = 0; k0 < NIN; k0 += 4) {
    float w0 = Ws[k0 + 0][j], w1 = Ws[k0 + 1][j];
    float w2 = Ws[k0 + 2][j], w3 = Ws[k0 + 3][j];
#pragma unroll
    for (int r = 0; r < 4; ++r) {
      float4 xv = *(const float4*)&xs[r4 + r][k0];
      acc[r] += xv.x * w0 + xv.y * w1 + xv.z * w2 + xv.w * w3;
    }
  }
  int h = j >> 4, c = j & 15;
  float as = att_src[h * NC + c], ad = att_dst[h * NC + c];
#pragma unroll
  for (int r = 0; r < 4; ++r) {
    int gr = row0 + r4 + r;
    float v = acc[r];
    float ps = v * as, pd = v * ad;
#pragma unroll
    for (int off = 8; off >= 1; off >>= 1) {
      ps += __shfl_xor(ps, off, 64);
      pd += __shfl_xor(pd, off, 64);
    }
    xwb[(size_t)gr * HC + j] = f2bf(v);
    if (c == 0) {
      a_src[gr * NH + h] = ps;
      a_dst[gr * NH + h] = pd;
    }
  }
}

// Pass A: read edges ONCE, bin by dst partition. Per-wave LDS stacks with
// ballot compaction; flush 64-at-a-time with a single chunky reservation
// atomic (12.5k atomics total, coalesced 4B-record writes). Record packs
// s (17b) | d_rel (13b) into one uint.
__global__ __launch_bounds__(256) void k_bin(const int* __restrict__ ei,
                                             int* __restrict__ binctr,
                                             unsigned* __restrict__ bin) {
  __shared__ unsigned st[4][NPART][128];  // 4 waves x 8 parts x 128 x 4B = 16 KB
  int tid = threadIdx.x, lane = tid & 63, wv = tid >> 6;
  unsigned long long lt = (1ull << lane) - 1ull;
  const int4* s4p = (const int4*)ei;
  const int4* d4p = (const int4*)(ei + NE);
  int cnt[NPART] = {0, 0, 0, 0, 0, 0, 0, 0};  // wave-uniform (ballot-derived)
  for (int it = 0; it < BNITER; ++it) {
    int g = blockIdx.x * 256 + tid + it * (BNBLK * 256);
    bool valid = g < NGROUPS;
    int4 d4 = valid ? d4p[g] : make_int4(-1, -1, -1, -1);
    int4 s4 = valid ? s4p[g] : make_int4(0, 0, 0, 0);
#pragma unroll
    for (int c = 0; c < 4; ++c) {
      int d = (c == 0) ? d4.x : (c == 1) ? d4.y : (c == 2) ? d4.z : d4.w;
      int s = (c == 0) ? s4.x : (c == 1) ? s4.y : (c == 2) ? s4.z : s4.w;
      unsigned part = (unsigned)d / DPP;  // d<0 -> huge -> no partition
#pragma unroll
      for (int p = 0; p < NPART; ++p) {
        bool mine = (part == (unsigned)p);
        unsigned long long m = __ballot(mine);
        if (m) {
          if (mine)
            st[wv][p][cnt[p] + (int)__popcll(m & lt)] =
                (unsigned)s | ((unsigned)(d - p * DPP) << 17);
          cnt[p] += (int)__popcll(m);
          if (cnt[p] >= 64) {
            cnt[p] -= 64;
            int base = 0;
            if (lane == 0) base = atomicAdd(&binctr[p], 64);
            base = __shfl(base, 0, 64);
            if (base + 64 <= BINCAP)
              bin[p * BINCAP + base + lane] = st[wv][p][cnt[p] + lane];
          }
        }
      }
    }
  }
#pragma unroll
  for (int p = 0; p < NPART; ++p) {
    if (cnt[p] > 0) {
      int base = 0;
      if (lane == 0) base = atomicAdd(&binctr[p], cnt[p]);
      base = __shfl(base, 0, 64);
      if (lane < cnt[p] && base + cnt[p] <= BINCAP)
        bin[p * BINCAP + base + lane] = st[wv][p][lane];
    }
  }
}

// Pass B: partition p's blocks (XCD-affine, blockIdx&7) consume bin[p] at
// full lane width: slot scatter + fused score. All writes/atomics L2-local.
__global__ __launch_bounds__(256) void k_scatter2(
    const int* __restrict__ binctr, const unsigned* __restrict__ bin,
    int* __restrict__ cnt, int* __restrict__ ss_slot, uint2* __restrict__ scr_slot,
    int* __restrict__ ofcnt, uint4* __restrict__ of,
    const float* __restrict__ a_src, const float* __restrict__ a_dst) {
  int p = blockIdx.x & (NPART - 1);
  int chunk = blockIdx.x >> 3;  // 0..S2CHUNK-1
  int n = min(binctr[p], BINCAP);
  for (int i = chunk * 256 + threadIdx.x; i < n; i += S2CHUNK * 256) {
    unsigned r = bin[p * BINCAP + i];
    int s = (int)(r & 0x1FFFFu);
    int d = p * DPP + (int)(r >> 17);
    int pos = atomicAdd(&cnt[d], 1);
    float4 av = *(const float4*)(a_src + (size_t)s * NH);  // random, L2/L3
    float4 dv = *(const float4*)(a_dst + (size_t)d * NH);  // partition-local
    unsigned a01 = (unsigned)f2bf(lrelu_exp(av.x + dv.x)) |
                   ((unsigned)f2bf(lrelu_exp(av.y + dv.y)) << 16);
    unsigned a23 = (unsigned)f2bf(lrelu_exp(av.z + dv.z)) |
                   ((unsigned)f2bf(lrelu_exp(av.w + dv.w)) << 16);
    if (pos < CAP) {
      int slot = d * CAP + pos;
      ss_slot[slot] = s;
      scr_slot[slot] = make_uint2(a01, a23);
    } else {
      int op = atomicAdd(ofcnt, 1);
      if (op < OFCAP) of[op] = make_uint4((unsigned)s, a01, a23, (unsigned)d);
    }
  }
}

// one wave per destination node, single sweep over the dst's slot run
// (contiguous at d*CAP), alphas precomputed. Overflow list replayed at the
// end (expected ~tens of entries total). XCD-affine mapping.
// Lane layout head-major: lane j = head (j>>4) x slot (j&15).
__global__ __launch_bounds__(256) void k_gat(
    const int* __restrict__ cnt, const int* __restrict__ ss_slot,
    const uint2* __restrict__ scr_slot,
    const int* __restrict__ ofcnt, const uint4* __restrict__ of,
    const float* __restrict__ a_src, const float* __restrict__ a_dst,
    const ushort* __restrict__ xwb, const float* __restrict__ bias,
    float* __restrict__ out) {
  int tid = threadIdx.x;
  int wv = tid >> 6, j = tid & 63;
  int p = blockIdx.x & (NPART - 1);
  int idx = blockIdx.x >> 3;  // 0..GPB-1
  int dd = idx * 4 + wv;
  if (dd >= DPP) return;      // tail block: 2 idle waves
  int d = p * DPP + dd;
  int h = j >> 4, sl = j & 15;
  int base = d * CAP;
  int deg = min(cnt[d], CAP);  // cnt may exceed CAP (overflowed arrivals)

  float ws = lrelu_exp(a_src[(size_t)d * NH + h] + a_dst[(size_t)d * NH + h]);
  float lsum = (sl == 0) ? ws : 0.f;           // per-lane partial denominator
  float acc = ws * bf2f(xwb[(size_t)d * HC + j]);  // self contribution

  for (int i0 = 0; i0 < deg; i0 += 16) {
    int nb = min(16, deg - i0);
    int s_j = 0;
    float al = 0.f;
    if (sl < nb) {
      s_j = ss_slot[base + i0 + sl];         // coalesced 4B
      uint2 q = scr_slot[base + i0 + sl];    // coalesced 8B
      unsigned packed = (h & 2) ? q.y : q.x;
      ushort ab = (h & 1) ? (ushort)(packed >> 16) : (ushort)(packed & 0xFFFFu);
      al = bf2f(ab);
    }
    lsum += al;
    if (nb == 16) {
#pragma unroll
      for (int k = 0; k < 16; ++k) {
        int s = __builtin_amdgcn_readlane(s_j, k);  // groups replicate -> uniform
        float alpha = __shfl(al, k, 16);
        acc += alpha * bf2f(xwb[(size_t)s * HC + j]);
      }
    } else {
      for (int k = 0; k < nb; ++k) {
        int s = __shfl(s_j, k, 16);
        float alpha = __shfl(al, k, 16);
        acc += alpha * bf2f(xwb[(size_t)s * HC + j]);
      }
    }
  }
  // overflow replay (tiny; all-lane cached reads, match on d)
  int oc = min(*ofcnt, OFCAP);
  for (int e = 0; e < oc; ++e) {
    uint4 r = of[e];
    if ((int)r.w == d) {
      unsigned packed = (h & 2) ? r.z : r.y;
      ushort ab = (h & 1) ? (ushort)(packed >> 16) : (ushort)(packed & 0xFFFFu);
      float al = bf2f(ab);
      if (sl == 0) lsum += al;
      acc += al * bf2f(xwb[(size_t)r.x * HC + j]);
    }
  }
  float L = lsum;
#pragma unroll
  for (int off = 8; off >= 1; off >>= 1) L += __shfl_xor(L, off, 64);
  out[(size_t)d * HC + j] = acc / (L + 1e-16f) + bias[j];
}

extern "C" void kernel_launch(void* const* d_in, const int* in_sizes, int n_in,
                              void* d_out, int out_size, void* d_ws, size_t ws_size,
                              hipStream_t stream) {
  const float* x       = (const float*)d_in[0];
  const int*   ei      = (const int*)d_in[1];
  // d_in[2] = edge_attr: ignored by the reference layer
  const float* W       = (const float*)d_in[3];
  const float* att_src = (const float*)d_in[4];
  const float* att_dst = (const float*)d_in[5];
  const float* bias    = (const float*)d_in[6];
  float* out = (float*)d_out;

  char* p = (char*)d_ws;
  ushort*   xwb     = (ushort*)p;   p += (size_t)NN * HC * 2;      // 6.4 MB
  float*    a_src   = (float*)p;    p += (size_t)NN * NH * 4;      // 0.8 MB
  float*    a_dst   = (float*)p;    p += (size_t)NN * NH * 4;      // 0.8 MB
  int*      cnt     = (int*)p;      p += (size_t)NN * 4;           // 0.2 MB
  int*      binctr  = (int*)p;      p += 64;                       // 8 + pad
  int*      ofcnt   = (int*)p;      p += 64;                       // 1 + pad
  int*      ss_slot = (int*)p;      p += (size_t)NN * CAP * 4;     // 6.4 MB
  uint2*    scr_slot= (uint2*)p;    p += (size_t)NN * CAP * 8;     // 12.8 MB
  uint4*    of      = (uint4*)p;    p += (size_t)OFCAP * 16;       // 16 KB
  unsigned* bin     = (unsigned*)p; p += (size_t)NPART * BINCAP * 4;  // 3.3 MB

  k_xw<<<NN / RPB, 256, 0, stream>>>(x, W, att_src, att_dst,
                                     xwb, a_src, a_dst, cnt, binctr, ofcnt);
  k_bin<<<BNBLK, 256, 0, stream>>>(ei, binctr, bin);
  k_scatter2<<<NPART * S2CHUNK, 256, 0, stream>>>(binctr, bin, cnt, ss_slot,
                                                  scr_slot, ofcnt, of,
                                                  a_src, a_dst);
  k_gat<<<NPART * GPB, 256, 0, stream>>>(cnt, ss_slot, scr_slot, ofcnt, of,
                                         a_src, a_dst, xwb, bias, out);
}

// Round 19
// 124.041 us; speedup vs baseline: 2.8948x; 2.8948x over previous
//
#include <hip/hip_runtime.h>

// GATConv: N=50000, NIN=128, H=4, C=16 (HC=64), E=800000 (+N self-loops,
// synthesized inside k_gat). Slot-table aggregation (no CSR). Edge list is
// pre-PACKED to one uint per edge (s|d<<16; both ids < 2^16) so k_scatter's
// 8x partition re-read streams 25.6MB instead of 51MB (r17 pacer arithmetic).
// r18 lesson: LDS/ballot binning serializes catastrophically — keep it dumb.
#define NN 50000
#define NIN 128
#define NH 4
#define NC 16
#define HC 64
#define NE 800000
#define NEG_SLOPE 0.2f
#define RPB 16                       // rows per block in k_xw (LDS 40KB -> 4 blk/CU)
#define NPART 8                      // dst partitions (== XCD count)
#define SCHUNK 256                   // blocks per partition in k_scatter
#define DPP (NN / NPART)             // 6250 dst per partition
#define GPB 1563                     // gat blocks per partition = ceil(6250/4)
#define CAP 32                       // slots per destination
#define OFCAP 8192                   // overflow list capacity (safety margin)

__device__ __forceinline__ ushort f2bf(float v) {  // RNE f32->bf16
  unsigned u = __float_as_uint(v);
  return (ushort)((u + 0x7FFFu + ((u >> 16) & 1u)) >> 16);
}
__device__ __forceinline__ float bf2f(ushort b) {
  return __uint_as_float((unsigned)b << 16);
}
__device__ __forceinline__ float lrelu_exp(float e) {
  e = e > 0.f ? e : NEG_SLOPE * e;
  return __expf(fminf(e, 60.f));  // no max-shift needed: |e|<~12 on this data
}

// xw(bf16) = x @ W (Ws+xs in LDS, 16 rows/block, 4 rows/thread), att dots fused.
// Also zeroes cnt[] and ofcnt (free ride; k_scatter runs strictly after).
__global__ __launch_bounds__(256, 4) void k_xw(
    const float* __restrict__ x, const float* __restrict__ W,
    const float* __restrict__ att_src, const float* __restrict__ att_dst,
    ushort* __restrict__ xwb, float* __restrict__ a_src, float* __restrict__ a_dst,
    int* __restrict__ cnt, int* __restrict__ ofcnt) {
  __shared__ float Ws[NIN][HC];   // 32 KB
  __shared__ float xs[RPB][NIN];  // 8 KB
  int tid = threadIdx.x;
  int gi = blockIdx.x * 256 + tid;
  if (gi < NN) cnt[gi] = 0;
  if (gi == 0) *ofcnt = 0;
  int row0 = blockIdx.x * RPB;  // NN % RPB == 0
  {
    const float4* wsrc = (const float4*)W;
    float4* wdst = (float4*)&Ws[0][0];
    for (int i = tid; i < NIN * HC / 4; i += 256) wdst[i] = wsrc[i];
    const float4* xsrc = (const float4*)(x + (size_t)row0 * NIN);
    float4* xdst = (float4*)&xs[0][0];
    for (int i = tid; i < RPB * (NIN / 4); i += 256) xdst[i] = xsrc[i];
  }
  __syncthreads();
  int j = tid & 63;
  int r4 = (tid >> 6) * 4;  // this wave's 4 rows
  float acc[4] = {0.f, 0.f, 0.f, 0.f};
#pragma unroll 2
  for (int k0 = 0; k0 < NIN; k0 += 4) {
    float w0 = Ws[k0 + 0][j], w1 = Ws[k0 + 1][j];
    float w2 = Ws[k0 + 2][j], w3 = Ws[k0 + 3][j];
#pragma unroll
    for (int r = 0; r < 4; ++r) {
      float4 xv = *(const float4*)&xs[r4 + r][k0];
      acc[r] += xv.x * w0 + xv.y * w1 + xv.z * w2 + xv.w * w3;
    }
  }
  int h = j >> 4, c = j & 15;
  float as = att_src[h * NC + c], ad = att_dst[h * NC + c];
#pragma unroll
  for (int r = 0; r < 4; ++r) {
    int gr = row0 + r4 + r;
    float v = acc[r];
    float ps = v * as, pd = v * ad;
#pragma unroll
    for (int off = 8; off >= 1; off >>= 1) {
      ps += __shfl_xor(ps, off, 64);
      pd += __shfl_xor(pd, off, 64);
    }
    xwb[(size_t)gr * HC + j] = f2bf(v);
    if (c == 0) {
      a_src[gr * NH + h] = ps;
      a_dst[gr * NH + h] = pd;
    }
  }
}

// pack each edge into one uint: s | d<<16 (both < 50000 < 2^16).
// Pure elementwise stream: 6.4MB read, 3.2MB write, no atomics.
__global__ __launch_bounds__(256) void k_pack(const int* __restrict__ ei,
                                              unsigned* __restrict__ pk) {
  int g = blockIdx.x * blockDim.x + threadIdx.x;
  if (g >= NE / 4) return;
  int4 s4 = ((const int4*)ei)[g];
  int4 d4 = ((const int4*)(ei + NE))[g];
  uint4 r;
  r.x = (unsigned)s4.x | ((unsigned)d4.x << 16);
  r.y = (unsigned)s4.y | ((unsigned)d4.y << 16);
  r.z = (unsigned)s4.z | ((unsigned)d4.z << 16);
  r.w = (unsigned)s4.w | ((unsigned)d4.w << 16);
  ((uint4*)pk)[g] = r;
}

// dst-partitioned slot scatter with fused score, consuming the PACKED edge
// stream (half the re-read bytes of r17). pos = atomicAdd(cnt[d]); write
// ss_slot/scr_slot[d*CAP+pos]. Overflow -> tiny list replayed by k_gat.
// XCD-affine: block b serves partition b&7 so slot regions stay L2-local.
__global__ __launch_bounds__(256) void k_scatter(
    const unsigned* __restrict__ pk, int* __restrict__ cnt,
    int* __restrict__ ss_slot, uint2* __restrict__ scr_slot,
    int* __restrict__ ofcnt, uint4* __restrict__ of,
    const float* __restrict__ a_src, const float* __restrict__ a_dst) {
  int p = blockIdx.x & (NPART - 1);
  int chunk = blockIdx.x >> 3;  // 0..SCHUNK-1
  int dlo = p * DPP, dhi = dlo + DPP;
  const uint4* p4 = (const uint4*)pk;
  const int ngroups = NE / 4;  // 200000
  for (int g = chunk * 256 + threadIdx.x; g < ngroups; g += SCHUNK * 256) {
    uint4 r4 = p4[g];
#pragma unroll
    for (int c = 0; c < 4; ++c) {
      unsigned r = (c == 0) ? r4.x : (c == 1) ? r4.y : (c == 2) ? r4.z : r4.w;
      int d = (int)(r >> 16);
      int s = (int)(r & 0xFFFFu);
      if (d >= dlo && d < dhi) {
        int pos = atomicAdd(&cnt[d], 1);
        float4 av = *(const float4*)(a_src + (size_t)s * NH);  // random, L2
        float4 dv = *(const float4*)(a_dst + (size_t)d * NH);  // L2-local
        unsigned a01 = (unsigned)f2bf(lrelu_exp(av.x + dv.x)) |
                       ((unsigned)f2bf(lrelu_exp(av.y + dv.y)) << 16);
        unsigned a23 = (unsigned)f2bf(lrelu_exp(av.z + dv.z)) |
                       ((unsigned)f2bf(lrelu_exp(av.w + dv.w)) << 16);
        if (pos < CAP) {
          int slot = d * CAP + pos;
          ss_slot[slot] = s;
          scr_slot[slot] = make_uint2(a01, a23);
        } else {
          int op = atomicAdd(ofcnt, 1);
          if (op < OFCAP) of[op] = make_uint4((unsigned)s, a01, a23, (unsigned)d);
        }
      }
    }
  }
}

// one wave per destination node, single sweep over the dst's slot run
// (contiguous at d*CAP), alphas precomputed. Overflow list replayed at the
// end (expected ~tens of entries total). XCD-affine mapping.
// Lane layout head-major: lane j = head (j>>4) x slot (j&15).
__global__ __launch_bounds__(256) void k_gat(
    const int* __restrict__ cnt, const int* __restrict__ ss_slot,
    const uint2* __restrict__ scr_slot,
    const int* __restrict__ ofcnt, const uint4* __restrict__ of,
    const float* __restrict__ a_src, const float* __restrict__ a_dst,
    const ushort* __restrict__ xwb, const float* __restrict__ bias,
    float* __restrict__ out) {
  int tid = threadIdx.x;
  int wv = tid >> 6, j = tid & 63;
  int p = blockIdx.x & (NPART - 1);
  int idx = blockIdx.x >> 3;  // 0..GPB-1
  int dd = idx * 4 + wv;
  if (dd >= DPP) return;      // tail block: 2 idle waves
  int d = p * DPP + dd;
  int h = j >> 4, sl = j & 15;
  int base = d * CAP;
  int deg = min(cnt[d], CAP);  // cnt may exceed CAP (overflowed arrivals)

  float ws = lrelu_exp(a_src[(size_t)d * NH + h] + a_dst[(size_t)d * NH + h]);
  float lsum = (sl == 0) ? ws : 0.f;           // per-lane partial denominator
  float acc = ws * bf2f(xwb[(size_t)d * HC + j]);  // self contribution

  for (int i0 = 0; i0 < deg; i0 += 16) {
    int nb = min(16, deg - i0);
    int s_j = 0;
    float al = 0.f;
    if (sl < nb) {
      s_j = ss_slot[base + i0 + sl];         // coalesced 4B
      uint2 q = scr_slot[base + i0 + sl];    // coalesced 8B
      unsigned packed = (h & 2) ? q.y : q.x;
      ushort ab = (h & 1) ? (ushort)(packed >> 16) : (ushort)(packed & 0xFFFFu);
      al = bf2f(ab);
    }
    lsum += al;
    if (nb == 16) {
#pragma unroll
      for (int k = 0; k < 16; ++k) {
        int s = __builtin_amdgcn_readlane(s_j, k);  // groups replicate -> uniform
        float alpha = __shfl(al, k, 16);
        acc += alpha * bf2f(xwb[(size_t)s * HC + j]);
      }
    } else {
      for (int k = 0; k < nb; ++k) {
        int s = __shfl(s_j, k, 16);
        float alpha = __shfl(al, k, 16);
        acc += alpha * bf2f(xwb[(size_t)s * HC + j]);
      }
    }
  }
  // overflow replay (tiny; all-lane cached reads, match on d)
  int oc = min(*ofcnt, OFCAP);
  for (int e = 0; e < oc; ++e) {
    uint4 r = of[e];
    if ((int)r.w == d) {
      unsigned packed = (h & 2) ? r.z : r.y;
      ushort ab = (h & 1) ? (ushort)(packed >> 16) : (ushort)(packed & 0xFFFFu);
      float al = bf2f(ab);
      if (sl == 0) lsum += al;
      acc += al * bf2f(xwb[(size_t)r.x * HC + j]);
    }
  }
  float L = lsum;
#pragma unroll
  for (int off = 8; off >= 1; off >>= 1) L += __shfl_xor(L, off, 64);
  out[(size_t)d * HC + j] = acc / (L + 1e-16f) + bias[j];
}

extern "C" void kernel_launch(void* const* d_in, const int* in_sizes, int n_in,
                              void* d_out, int out_size, void* d_ws, size_t ws_size,
                              hipStream_t stream) {
  const float* x       = (const float*)d_in[0];
  const int*   ei      = (const int*)d_in[1];
  // d_in[2] = edge_attr: ignored by the reference layer
  const float* W       = (const float*)d_in[3];
  const float* att_src = (const float*)d_in[4];
  const float* att_dst = (const float*)d_in[5];
  const float* bias    = (const float*)d_in[6];
  float* out = (float*)d_out;

  char* p = (char*)d_ws;
  ushort*   xwb     = (ushort*)p;   p += (size_t)NN * HC * 2;    // 6.4 MB
  float*    a_src   = (float*)p;    p += (size_t)NN * NH * 4;    // 0.8 MB
  float*    a_dst   = (float*)p;    p += (size_t)NN * NH * 4;    // 0.8 MB
  int*      cnt     = (int*)p;      p += (size_t)NN * 4;         // 0.2 MB
  int*      ofcnt   = (int*)p;      p += 64;                     // 1 + pad
  int*      ss_slot = (int*)p;      p += (size_t)NN * CAP * 4;   // 6.4 MB
  uint2*    scr_slot= (uint2*)p;    p += (size_t)NN * CAP * 8;   // 12.8 MB
  uint4*    of      = (uint4*)p;    p += (size_t)OFCAP * 16;     // 0.13 MB
  unsigned* pk      = (unsigned*)p; p += (size_t)NE * 4;         // 3.2 MB

  k_xw<<<NN / RPB, 256, 0, stream>>>(x, W, att_src, att_dst,
                                     xwb, a_src, a_dst, cnt, ofcnt);
  k_pack<<<(NE / 4 + 255) / 256, 256, 0, stream>>>(ei, pk);
  k_scatter<<<NPART * SCHUNK, 256, 0, stream>>>(pk, cnt, ss_slot, scr_slot,
                                                ofcnt, of, a_src, a_dst);
  k_gat<<<NPART * GPB, 256, 0, stream>>>(cnt, ss_slot, scr_slot, ofcnt, of,
                                         a_src, a_dst, xwb, bias, out);
}

// Round 20
// 123.567 us; speedup vs baseline: 2.9059x; 1.0038x over previous
//
#include <hip/hip_runtime.h>

// GATConv: N=50000, NIN=128, H=4, C=16 (HC=64), E=800000 (+N self-loops,
// synthesized inside k_gat). Slot-table aggregation (no CSR), packed edges
// (s|d<<16). r19 lesson: score-precompute is a wash in k_gat (xwb gathers
// dominate; a_src is L2-resident) and bloats scatter — so scatter is now the
// true minimum: atomic cursor + one 4B store per edge; k_gat recomputes alpha.
#define NN 50000
#define NIN 128
#define NH 4
#define NC 16
#define HC 64
#define NE 800000
#define NEG_SLOPE 0.2f
#define RPB 16                       // rows per block in k_xw (LDS 40KB -> 4 blk/CU)
#define NPART 8                      // dst partitions (== XCD count)
#define SCHUNK 256                   // blocks per partition in k_scatter
#define DPP (NN / NPART)             // 6250 dst per partition
#define GPB 1563                     // gat blocks per partition = ceil(6250/4)
#define CAP 32                       // slots per destination
#define OFCAP 8192                   // overflow list capacity (safety margin)

__device__ __forceinline__ ushort f2bf(float v) {  // RNE f32->bf16
  unsigned u = __float_as_uint(v);
  return (ushort)((u + 0x7FFFu + ((u >> 16) & 1u)) >> 16);
}
__device__ __forceinline__ float bf2f(ushort b) {
  return __uint_as_float((unsigned)b << 16);
}
__device__ __forceinline__ float lrelu_exp(float e) {
  e = e > 0.f ? e : NEG_SLOPE * e;
  return __expf(fminf(e, 60.f));  // no max-shift needed: |e|<~12 on this data
}

// xw(bf16) = x @ W (Ws+xs in LDS, 16 rows/block, 4 rows/thread), att dots fused.
// Also zeroes cnt[] and ofcnt (free ride; k_scatter runs strictly after).
__global__ __launch_bounds__(256, 4) void k_xw(
    const float* __restrict__ x, const float* __restrict__ W,
    const float* __restrict__ att_src, const float* __restrict__ att_dst,
    ushort* __restrict__ xwb, float* __restrict__ a_src, float* __restrict__ a_dst,
    int* __restrict__ cnt, int* __restrict__ ofcnt) {
  __shared__ float Ws[NIN][HC];   // 32 KB
  __shared__ float xs[RPB][NIN];  // 8 KB
  int tid = threadIdx.x;
  int gi = blockIdx.x * 256 + tid;
  if (gi < NN) cnt[gi] = 0;
  if (gi == 0) *ofcnt = 0;
  int row0 = blockIdx.x * RPB;  // NN % RPB == 0
  {
    const float4* wsrc = (const float4*)W;
    float4* wdst = (float4*)&Ws[0][0];
    for (int i = tid; i < NIN * HC / 4; i += 256) wdst[i] = wsrc[i];
    const float4* xsrc = (const float4*)(x + (size_t)row0 * NIN);
    float4* xdst = (float4*)&xs[0][0];
    for (int i = tid; i < RPB * (NIN / 4); i += 256) xdst[i] = xsrc[i];
  }
  __syncthreads();
  int j = tid & 63;
  int r4 = (tid >> 6) * 4;  // this wave's 4 rows
  float acc[4] = {0.f, 0.f, 0.f, 0.f};
#pragma unroll 2
  for (int k0 = 0; k0 < NIN; k0 += 4) {
    float w0 = Ws[k0 + 0][j], w1 = Ws[k0 + 1][j];
    float w2 = Ws[k0 + 2][j], w3 = Ws[k0 + 3][j];
#pragma unroll
    for (int r = 0; r < 4; ++r) {
      float4 xv = *(const float4*)&xs[r4 + r][k0];
      acc[r] += xv.x * w0 + xv.y * w1 + xv.z * w2 + xv.w * w3;
    }
  }
  int h = j >> 4, c = j & 15;
  float as = att_src[h * NC + c], ad = att_dst[h * NC + c];
#pragma unroll
  for (int r = 0; r < 4; ++r) {
    int gr = row0 + r4 + r;
    float v = acc[r];
    float ps = v * as, pd = v * ad;
#pragma unroll
    for (int off = 8; off >= 1; off >>= 1) {
      ps += __shfl_xor(ps, off, 64);
      pd += __shfl_xor(pd, off, 64);
    }
    xwb[(size_t)gr * HC + j] = f2bf(v);
    if (c == 0) {
      a_src[gr * NH + h] = ps;
      a_dst[gr * NH + h] = pd;
    }
  }
}

// pack each edge into one uint: s | d<<16 (both < 50000 < 2^16).
// Pure elementwise stream: 6.4MB read, 3.2MB write, no atomics.
__global__ __launch_bounds__(256) void k_pack(const int* __restrict__ ei,
                                              unsigned* __restrict__ pk) {
  int g = blockIdx.x * blockDim.x + threadIdx.x;
  if (g >= NE / 4) return;
  int4 s4 = ((const int4*)ei)[g];
  int4 d4 = ((const int4*)(ei + NE))[g];
  uint4 r;
  r.x = (unsigned)s4.x | ((unsigned)d4.x << 16);
  r.y = (unsigned)s4.y | ((unsigned)d4.y << 16);
  r.z = (unsigned)s4.z | ((unsigned)d4.z << 16);
  r.w = (unsigned)s4.w | ((unsigned)d4.w << 16);
  ((uint4*)pk)[g] = r;
}

// dst-partitioned slot scatter, TRUE MINIMUM: packed-stream read (L3-resident
// on re-read), cursor atomic, one 4B store. No gathers, no exp, no score.
// XCD-affine: block b serves partition b&7 so slot regions stay L2-local.
__global__ __launch_bounds__(256) void k_scatter(
    const unsigned* __restrict__ pk, int* __restrict__ cnt,
    ushort* __restrict__ ss_slot,
    int* __restrict__ ofcnt, unsigned* __restrict__ of) {
  int p = blockIdx.x & (NPART - 1);
  int chunk = blockIdx.x >> 3;  // 0..SCHUNK-1
  int dlo = p * DPP, dhi = dlo + DPP;
  const uint4* p4 = (const uint4*)pk;
  const int ngroups = NE / 4;  // 200000
  for (int g = chunk * 256 + threadIdx.x; g < ngroups; g += SCHUNK * 256) {
    uint4 r4 = p4[g];
#pragma unroll
    for (int c = 0; c < 4; ++c) {
      unsigned r = (c == 0) ? r4.x : (c == 1) ? r4.y : (c == 2) ? r4.z : r4.w;
      int d = (int)(r >> 16);
      if (d >= dlo && d < dhi) {
        int pos = atomicAdd(&cnt[d], 1);
        if (pos < CAP) {
          ss_slot[d * CAP + pos] = (ushort)(r & 0xFFFFu);
        } else {
          int op = atomicAdd(ofcnt, 1);
          if (op < OFCAP) of[op] = r;
        }
      }
    }
  }
}

// one wave per destination node, single sweep over the dst's slot run
// (contiguous at d*CAP); alpha recomputed from a_src gather (0.8MB L2-resident
// table) + exp — r10-style, measured equal to precomputed-scr in k_gat.
// Overflow list replayed at the end. XCD-affine mapping.
// Lane layout head-major: lane j = head (j>>4) x slot (j&15).
__global__ __launch_bounds__(256) void k_gat(
    const int* __restrict__ cnt, const ushort* __restrict__ ss_slot,
    const int* __restrict__ ofcnt, const unsigned* __restrict__ of,
    const float* __restrict__ a_src, const float* __restrict__ a_dst,
    const ushort* __restrict__ xwb, const float* __restrict__ bias,
    float* __restrict__ out) {
  int tid = threadIdx.x;
  int wv = tid >> 6, j = tid & 63;
  int p = blockIdx.x & (NPART - 1);
  int idx = blockIdx.x >> 3;  // 0..GPB-1
  int dd = idx * 4 + wv;
  if (dd >= DPP) return;      // tail block: 2 idle waves
  int d = p * DPP + dd;
  int h = j >> 4, sl = j & 15;
  int base = d * CAP;
  int deg = min(cnt[d], CAP);  // cnt may exceed CAP (overflowed arrivals)

  float adr = a_dst[(size_t)d * NH + h];
  float ws = lrelu_exp(a_src[(size_t)d * NH + h] + adr);  // self score
  float lsum = (sl == 0) ? ws : 0.f;           // per-lane partial denominator
  float acc = ws * bf2f(xwb[(size_t)d * HC + j]);  // self contribution

  for (int i0 = 0; i0 < deg; i0 += 16) {
    int nb = min(16, deg - i0);
    int s_j = 0;
    float al = 0.f;
    if (sl < nb) {
      s_j = (int)ss_slot[base + i0 + sl];                  // coalesced 2B
      al = lrelu_exp(a_src[(size_t)s_j * NH + h] + adr);   // L2-resident gather
    }
    lsum += al;
    if (nb == 16) {
#pragma unroll
      for (int k = 0; k < 16; ++k) {
        int s = __builtin_amdgcn_readlane(s_j, k);  // lane k holds slot k
        float alpha = __shfl(al, k, 16);
        acc += alpha * bf2f(xwb[(size_t)s * HC + j]);
      }
    } else {
      for (int k = 0; k < nb; ++k) {
        int s = __shfl(s_j, k, 16);
        float alpha = __shfl(al, k, 16);
        acc += alpha * bf2f(xwb[(size_t)s * HC + j]);
      }
    }
  }
  // overflow replay (tiny; all-lane cached reads, match on d, recompute alpha)
  int oc = min(*ofcnt, OFCAP);
  for (int e = 0; e < oc; ++e) {
    unsigned r = of[e];
    if ((int)(r >> 16) == d) {
      int s = (int)(r & 0xFFFFu);
      float al = lrelu_exp(a_src[(size_t)s * NH + h] + adr);
      if (sl == 0) lsum += al;
      acc += al * bf2f(xwb[(size_t)s * HC + j]);
    }
  }
  float L = lsum;
#pragma unroll
  for (int off = 8; off >= 1; off >>= 1) L += __shfl_xor(L, off, 64);
  out[(size_t)d * HC + j] = acc / (L + 1e-16f) + bias[j];
}

extern "C" void kernel_launch(void* const* d_in, const int* in_sizes, int n_in,
                              void* d_out, int out_size, void* d_ws, size_t ws_size,
                              hipStream_t stream) {
  const float* x       = (const float*)d_in[0];
  const int*   ei      = (const int*)d_in[1];
  // d_in[2] = edge_attr: ignored by the reference layer
  const float* W       = (const float*)d_in[3];
  const float* att_src = (const float*)d_in[4];
  const float* att_dst = (const float*)d_in[5];
  const float* bias    = (const float*)d_in[6];
  float* out = (float*)d_out;

  char* p = (char*)d_ws;
  ushort*   xwb     = (ushort*)p;   p += (size_t)NN * HC * 2;    // 6.4 MB
  float*    a_src   = (float*)p;    p += (size_t)NN * NH * 4;    // 0.8 MB
  float*    a_dst   = (float*)p;    p += (size_t)NN * NH * 4;    // 0.8 MB
  int*      cnt     = (int*)p;      p += (size_t)NN * 4;         // 0.2 MB
  int*      ofcnt   = (int*)p;      p += 64;                     // 1 + pad
  ushort*   ss_slot = (ushort*)p;   p += (size_t)NN * CAP * 2;   // 3.2 MB
  unsigned* of      = (unsigned*)p; p += (size_t)OFCAP * 4;      // 32 KB
  unsigned* pk      = (unsigned*)p; p += (size_t)NE * 4;         // 3.2 MB

  k_xw<<<NN / RPB, 256, 0, stream>>>(x, W, att_src, att_dst,
                                     xwb, a_src, a_dst, cnt, ofcnt);
  k_pack<<<(NE / 4 + 255) / 256, 256, 0, stream>>>(ei, pk);
  k_scatter<<<NPART * SCHUNK, 256, 0, stream>>>(pk, cnt, ss_slot, ofcnt, of);
  k_gat<<<NPART * GPB, 256, 0, stream>>>(cnt, ss_slot, ofcnt, of,
                                         a_src, a_dst, xwb, bias, out);
}